// Round 12
// baseline (57.888 us; speedup 1.0000x reference)
//
#include <hip/hip_runtime.h>

#define NCLS 24
#define NB 8
#define NCH 128
#define WLO 128
#define WHI 512
#define CELLS (128*128)
#define SUBT 256                    // subtiles (blocks) per batch
#define NBLK (NB * SUBT)            // 2048
#define KCH (NCLS * NCH)            // 3072
#define NF (NB * KCH)               // 24576

typedef _Float16 f16x8 __attribute__((ext_vector_type(8)));
typedef float    f32x4 __attribute__((ext_vector_type(4)));

// hist row swizzle: cell ^ ((cls&7)<<3) — spreads A-fragment row reads across
// banks (2-way = free); octet-aligned reads stay contiguous (XOR acts on bit>=3).
#define HSWZ(c_, e_) ((e_) ^ (((c_) & 7) << 3))

// ZERO-BARRIER kernel. Block = one 64-cell subtile, 4 waves. Each wave owns a
// PRIVATE 32x64 histogram (redundant label pass; waves 1-3 hit L1) and its own
// 32 channels, so no cross-wave LDS visibility is ever needed. B-fragments are
// read straight from global (native layout match), A-fragments from own hist.
__global__ __launch_bounds__(256, 4)
void fm_main(const float* __restrict__ data, const int* __restrict__ label,
             _Float16* __restrict__ part, float* __restrict__ cpart)
{
    __shared__ float hist4[4][32 * 64];       // 32 KB, wave-private slices

    const int bid  = blockIdx.x;
    const int b    = bid >> 8;
    const int grp  = bid & 255;               // subtile index
    const int tid  = threadIdx.x;

    const int w    = tid >> 6;
    const int lane = tid & 63;                // = cell within subtile
    const int l15  = lane & 15, lg = lane >> 4;
    const int wb   = w * 32;                  // this wave's channel base

    const int y  = grp >> 1;
    const int x0 = (grp & 1) << 6;
    const int cb = y * WLO + x0;              // flat cell base

    float* hist = hist4[w];

    // ---- issue label loads: own cell's 4 hi-res rows (waves 1-3: L1 hits) ----
    const int* lp = label + (size_t)b * (WHI * WHI) + (size_t)(4 * y) * WHI + 4 * x0 + 4 * lane;
    const int4 lv0 = *(const int4*)lp;
    const int4 lv1 = *(const int4*)(lp + WHI);
    const int4 lv2 = *(const int4*)(lp + 2 * WHI);
    const int4 lv3 = *(const int4*)(lp + 3 * WHI);

    // ---- issue B loads: data[ch = wb+nt*16+l15][cb + kt*32 + lg*8 ..+8] ----
    f32x4 bs[2][2][2];
    const float* dp = data + (size_t)b * NCH * CELLS + cb + lg * 8;
#pragma unroll
    for (int nt = 0; nt < 2; ++nt)
#pragma unroll
        for (int kt = 0; kt < 2; ++kt)
#pragma unroll
            for (int p = 0; p < 2; ++p)
                bs[nt][kt][p] = *(const f32x4*)(dp + (size_t)(wb + nt * 16 + l15) * CELLS
                                                   + kt * 32 + p * 4);
    __builtin_amdgcn_sched_barrier(0);   // pin: all 12 loads issued before DS work

    // ---- zero own hist (8 KB = 8 ds_write_b128 per lane) ----
#pragma unroll
    for (int j = 0; j < 8; ++j)
        *(f32x4*)&hist[lane * 4 + j * 256] = (f32x4){0.f, 0.f, 0.f, 0.f};

    // ---- 16 private-column atomics (lane-distinct addresses, 2/bank = free) ----
#define AH(v_) if ((unsigned)(v_) < 24u) atomicAdd(&hist[(v_) * 64 + HSWZ(v_, lane)], 1.f)
    AH(lv0.x); AH(lv0.y); AH(lv0.z); AH(lv0.w);
    AH(lv1.x); AH(lv1.y); AH(lv1.z); AH(lv1.w);
    AH(lv2.x); AH(lv2.y); AH(lv2.z); AH(lv2.w);
    AH(lv3.x); AH(lv3.y); AH(lv3.z); AH(lv3.w);
#undef AH

    // ---- A fragments from own hist (wave-local lgkm dep only, NO barrier) ----
    f16x8 af[2][2];
    float cs0 = 0.f, cs1 = 0.f;
#pragma unroll
    for (int mt = 0; mt < 2; ++mt)
#pragma unroll
        for (int kt = 0; kt < 2; ++kt) {
            const int cls = mt * 16 + l15;
            const int e0  = kt * 32 + lg * 8;
            const float* hp = &hist[cls * 64 + HSWZ(cls, e0)];
            const f32x4 h0 = *(const f32x4*)hp;
            const f32x4 h1 = *(const f32x4*)(hp + 4);
            f16x8 a;
            a[0] = (_Float16)h0.x; a[1] = (_Float16)h0.y; a[2] = (_Float16)h0.z; a[3] = (_Float16)h0.w;
            a[4] = (_Float16)h1.x; a[5] = (_Float16)h1.y; a[6] = (_Float16)h1.z; a[7] = (_Float16)h1.w;
            af[mt][kt] = a;
            const float p = (h0.x + h0.y) + (h0.z + h0.w) + (h1.x + h1.y) + (h1.z + h1.w);
            if (mt == 0) cs0 += p; else cs1 += p;
        }

    // ---- B fragments: cvt staged f32 -> f16 (vmcnt dep handled at use) ----
    f16x8 bf[2][2];
#pragma unroll
    for (int nt = 0; nt < 2; ++nt)
#pragma unroll
        for (int kt = 0; kt < 2; ++kt) {
            f16x8 v;
            v[0] = (_Float16)bs[nt][kt][0].x; v[1] = (_Float16)bs[nt][kt][0].y;
            v[2] = (_Float16)bs[nt][kt][0].z; v[3] = (_Float16)bs[nt][kt][0].w;
            v[4] = (_Float16)bs[nt][kt][1].x; v[5] = (_Float16)bs[nt][kt][1].y;
            v[6] = (_Float16)bs[nt][kt][1].z; v[7] = (_Float16)bs[nt][kt][1].w;
            bf[nt][kt] = v;
        }

    // ---- 8 MFMAs ----
    f32x4 acc[2][2];
#pragma unroll
    for (int mt = 0; mt < 2; ++mt)
#pragma unroll
        for (int nt = 0; nt < 2; ++nt) {
            acc[mt][nt] = (f32x4){0.f, 0.f, 0.f, 0.f};
#pragma unroll
            for (int kt = 0; kt < 2; ++kt)
                acc[mt][nt] = __builtin_amdgcn_mfma_f32_16x16x32_f16(
                    af[mt][kt], bf[nt][kt], acc[mt][nt], 0, 0, 0);
        }

    // ---- counts (identical across waves): butterfly lg-groups, wave 0 stores ----
    cs0 += __shfl_xor(cs0, 16, 64); cs0 += __shfl_xor(cs0, 32, 64);
    cs1 += __shfl_xor(cs1, 16, 64); cs1 += __shfl_xor(cs1, 32, 64);
    if (w == 0 && lane < 16) {
        cpart[(size_t)bid * NCLS + lane] = cs0;
        if (lane < 8) cpart[(size_t)bid * NCLS + 16 + lane] = cs1;
    }

    // ---- flush f16 per-block partials (non-atomic) ----
    _Float16* pblk = part + (size_t)bid * KCH;
#pragma unroll
    for (int mt = 0; mt < 2; ++mt)
#pragma unroll
        for (int nt = 0; nt < 2; ++nt)
#pragma unroll
            for (int rg = 0; rg < 4; ++rg) {
                const int cls = mt * 16 + lg * 4 + rg;        // C/D: row=(lane>>4)*4+reg
                const int ch  = wb + nt * 16 + l15;           //      col=lane&15
                if (cls < NCLS) pblk[cls * NCH + ch] = (_Float16)acc[mt][nt][rg];
            }
}

// Grid 384 = (b, cls, ch-half). 4 waves reduce 64 g's each -> LDS -> wave-0 finish.
__global__ __launch_bounds__(256)
void fm_final(const _Float16* __restrict__ part, const float* __restrict__ cpart,
              float* __restrict__ out)
{
    __shared__ float red[256];
    __shared__ float credv[256];
    const int bid  = blockIdx.x;
    const int b    = bid / (NCLS * 2);
    const int rem  = bid % (NCLS * 2);
    const int cls  = rem >> 1;
    const int half = rem & 1;
    const int t    = threadIdx.x;
    const int c    = t & 63;           // channel within half
    const int gq   = t >> 6;           // g-quarter 0..3

    credv[t] = cpart[(size_t)(b * SUBT + t) * NCLS + cls];

    const _Float16* pb = part + (size_t)(b * SUBT + gq * 64) * KCH + cls * NCH + half * 64 + c;
    float s = 0.f;
#pragma unroll 8
    for (int g = 0; g < 64; ++g) s += (float)pb[(size_t)g * KCH];
    red[t] = s;
    __syncthreads();

    if (t < 64) {
        float cnt = credv[t] + credv[t + 64] + credv[t + 128] + credv[t + 192];
#pragma unroll
        for (int o = 32; o >= 1; o >>= 1) cnt += __shfl_xor(cnt, o, 64);
        const float sf = red[t] + red[t + 64] + red[t + 128] + red[t + 192];
        out[(size_t)b * KCH + (half * 64 + t) * NCLS + cls] = sf / (cnt + 1e-8f);  // (B,C,NCLS)
        if (t == 0 && half == 0) out[NF + b * NCLS + cls] = (cnt > 0.f) ? 1.f : 0.f;
    }
}

extern "C" void kernel_launch(void* const* d_in, const int* in_sizes, int n_in,
                              void* d_out, int out_size, void* d_ws, size_t ws_size,
                              hipStream_t stream) {
    const float* data  = (const float*)d_in[0];
    const int*   label = (const int*)d_in[1];
    float*     out   = (float*)d_out;
    _Float16*  part  = (_Float16*)d_ws;                          // NBLK*3072 f16 (12.6 MB)
    float*     cpart = (float*)(part + (size_t)NBLK * KCH);      // NBLK*24 f32

    fm_main<<<dim3(NBLK), dim3(256), 0, stream>>>(data, label, part, cpart);
    fm_final<<<dim3(NB * NCLS * 2), dim3(256), 0, stream>>>(part, cpart, out);
}

// Round 13
// 27.459 us; speedup vs baseline: 2.1082x; 2.1082x over previous
//
#include <hip/hip_runtime.h>

#define NCLS 24
#define NB 8
#define NCH 128
#define WLO 128
#define WHI 512
#define CELLS (128*128)
#define SUBS 2                      // subtiles per block, register-accumulated
#define BPB 128                     // blocks per batch
#define NBLK (NB * BPB)             // 1024
#define KCH (NCLS * NCH)            // 3072
#define NF (NB * KCH)               // 24576

typedef _Float16 f16x4 __attribute__((ext_vector_type(4)));
typedef _Float16 f16x8 __attribute__((ext_vector_type(8)));
typedef float    f32x4 __attribute__((ext_vector_type(4)));

// hist row swizzle: cell ^ ((cls&7)<<3), 8-cell (32 B) granularity.
#define HSWZ(c_, e_) ((e_) ^ (((c_) & 7) << 3))

// LDS-visibility barrier WITHOUT the vmcnt(0) drain (global prefetches ride through).
__device__ __forceinline__ void barrier_nodrain() {
    asm volatile("s_waitcnt lgkmcnt(0)" ::: "memory");
    __builtin_amdgcn_s_barrier();
}

// One block = one 128-cell row = 2 subtiles of 64 cells, acc carried in regs.
__global__ __launch_bounds__(256, 4)
void fm_main(const float* __restrict__ data, const int* __restrict__ label,
             _Float16* __restrict__ part, float* __restrict__ cpart)
{
    __shared__ float    histf[32 * 64];       // 8 KB, rows 24-31 stay zero (A-pad)
    __shared__ _Float16 tile[NCH * 64];       // 16 KB, [ch][cell swz]

    // XCD-bijective swizzle: physical dispatch d -> XCD d%8; give each XCD a
    // CONTIGUOUS logical range (one batch) for L2 + DRAM-row locality.
    const int bid0 = blockIdx.x;
    const int bid  = (bid0 & 7) * (NBLK >> 3) + (bid0 >> 3);

    const int b    = bid >> 7;
    const int grp  = bid & 127;               // cell row
    const int tid  = threadIdx.x;

    const int q    = tid & 15;        // float4 slot (4 cells)
    const int chb  = tid >> 4;        // channel base 0..15
    const int r    = tid >> 6;        // label hi-res row 0..3
    const int cl   = tid & 63;        // label cell 0..63
    const int w    = tid >> 6;        // wave id
    const int lane = tid & 63;

    const float* dbase = data  + (size_t)b * NCH * CELLS;
    const int*   lbase = label + (size_t)b * (WHI * WHI) + (size_t)(4 * grp + r) * WHI;

    // ---- prologue: BOTH labels first (oldest in vmcnt), then subtile-0 data ----
    const int4 lv0 = *reinterpret_cast<const int4*>(lbase + cl * 4);
    const int4 lv1 = *reinterpret_cast<const int4*>(lbase + 256 + cl * 4);
    float4 v[8];
    {
        const int cb = grp * WLO;                 // x0 = 0
#pragma unroll
        for (int k = 0; k < 8; ++k)
            v[k] = *reinterpret_cast<const float4*>(dbase + (size_t)(chb + k * 16) * CELLS + cb + q * 4);
    }
    __builtin_amdgcn_sched_barrier(0);   // pin: all prologue loads issued here

    f32x4 acc[2][2];
#pragma unroll
    for (int mt = 0; mt < 2; ++mt)
#pragma unroll
        for (int nt = 0; nt < 2; ++nt) acc[mt][nt] = (f32x4){0.f, 0.f, 0.f, 0.f};
    float cs0 = 0.f, cs1 = 0.f;

#pragma unroll
    for (int s = 0; s < SUBS; ++s) {
        const int4 lv = (s == 0) ? lv0 : lv1;     // static under full unroll

        // ---- zero histogram ----
#pragma unroll
        for (int k = 0; k < 8; ++k) histf[tid + k * 256] = 0.f;
        barrier_nodrain();                    // B1

        // ---- histogram atomics (distinct cell per lane) ----
        if ((unsigned)lv.x < 24u) atomicAdd(&histf[lv.x * 64 + HSWZ(lv.x, cl)], 1.f);
        if ((unsigned)lv.y < 24u) atomicAdd(&histf[lv.y * 64 + HSWZ(lv.y, cl)], 1.f);
        if ((unsigned)lv.z < 24u) atomicAdd(&histf[lv.z * 64 + HSWZ(lv.z, cl)], 1.f);
        if ((unsigned)lv.w < 24u) atomicAdd(&histf[lv.w * 64 + HSWZ(lv.w, cl)], 1.f);

        // ---- stage f16 data tile, swizzled [ch][cell] ----
#pragma unroll
        for (int k = 0; k < 8; ++k) {
            const int ch = chb + k * 16;
            f16x4 hv;
            hv[0] = (_Float16)v[k].x; hv[1] = (_Float16)v[k].y;
            hv[2] = (_Float16)v[k].z; hv[3] = (_Float16)v[k].w;
            const int idx = ch * 64 + ((((q >> 1) ^ (ch & 7)) << 3) | ((q & 1) << 2));
            *reinterpret_cast<f16x4*>(&tile[idx]) = hv;
        }

        // ---- prefetch subtile-1 data (rides through barriers, pinned here) ----
        if (s + 1 < SUBS) {
            const int cb = grp * WLO + 64;            // x0 = 64
#pragma unroll
            for (int k = 0; k < 8; ++k)
                v[k] = *reinterpret_cast<const float4*>(dbase + (size_t)(chb + k * 16) * CELLS + cb + q * 4);
            __builtin_amdgcn_sched_barrier(0);        // pin issue before B2
        }
        barrier_nodrain();                    // B2: hist + tile visible

        // ---- A fragments from f32 histogram; count partials from same reads ----
        f16x8 af[2][2];
#pragma unroll
        for (int mt = 0; mt < 2; ++mt)
#pragma unroll
            for (int kt = 0; kt < 2; ++kt) {
                const int cls = mt * 16 + (lane & 15);
                const int e0  = kt * 32 + (lane >> 4) * 8;
                const float* hp = &histf[cls * 64 + HSWZ(cls, e0)];
                const f32x4 h0 = *reinterpret_cast<const f32x4*>(hp);
                const f32x4 h1 = *reinterpret_cast<const f32x4*>(hp + 4);
                f16x8 a;
                a[0] = (_Float16)h0.x; a[1] = (_Float16)h0.y; a[2] = (_Float16)h0.z; a[3] = (_Float16)h0.w;
                a[4] = (_Float16)h1.x; a[5] = (_Float16)h1.y; a[6] = (_Float16)h1.z; a[7] = (_Float16)h1.w;
                af[mt][kt] = a;
                const float p = (h0.x + h0.y) + (h0.z + h0.w) + (h1.x + h1.y) + (h1.z + h1.w);
                if (mt == 0) cs0 += p; else cs1 += p;
            }

        // ---- B fragments from tile ----
        f16x8 bf[2][2];
#pragma unroll
        for (int nt = 0; nt < 2; ++nt)
#pragma unroll
            for (int kt = 0; kt < 2; ++kt) {
                const int row = w * 32 + nt * 16 + (lane & 15);
                const int g   = kt * 4 + (lane >> 4);
                bf[nt][kt] = *reinterpret_cast<const f16x8*>(&tile[row * 64 + ((g ^ (row & 7)) << 3)]);
            }

        // ---- 8 MFMAs, accumulate across subtiles ----
#pragma unroll
        for (int mt = 0; mt < 2; ++mt)
#pragma unroll
            for (int nt = 0; nt < 2; ++nt)
#pragma unroll
                for (int kt = 0; kt < 2; ++kt)
                    acc[mt][nt] = __builtin_amdgcn_mfma_f32_16x16x32_f16(
                        af[mt][kt], bf[nt][kt], acc[mt][nt], 0, 0, 0);

        if (s + 1 < SUBS) barrier_nodrain();  // B3 only between subtiles
    }

    // ---- counts: butterfly over 4 k-groups; wave 0 lanes write ----
    cs0 += __shfl_xor(cs0, 16, 64); cs0 += __shfl_xor(cs0, 32, 64);
    cs1 += __shfl_xor(cs1, 16, 64); cs1 += __shfl_xor(cs1, 32, 64);
    if (w == 0 && lane < 16) {
        cpart[(size_t)bid * NCLS + lane] = cs0;
        if (lane < 8) cpart[(size_t)bid * NCLS + 16 + lane] = cs1;
    }

    // ---- flush f16 per-block partials (non-atomic), logical-bid indexed ----
    _Float16* pblk = part + (size_t)bid * KCH;
#pragma unroll
    for (int mt = 0; mt < 2; ++mt)
#pragma unroll
        for (int nt = 0; nt < 2; ++nt)
#pragma unroll
            for (int rg = 0; rg < 4; ++rg) {
                const int cls = mt * 16 + (lane >> 4) * 4 + rg;   // C/D: row=(lane>>4)*4+reg
                const int ch  = w * 32 + nt * 16 + (lane & 15);   //      col=lane&15
                if (cls < NCLS) pblk[cls * NCH + ch] = (_Float16)acc[mt][nt][rg];
            }
}

// Grid 384 = (b, cls, ch-half). 4 waves reduce 32 g's each -> LDS -> wave-0 finish.
__global__ __launch_bounds__(256)
void fm_final(const _Float16* __restrict__ part, const float* __restrict__ cpart,
              float* __restrict__ out)
{
    __shared__ float red[256];
    __shared__ float credv[128];
    const int bid  = blockIdx.x;
    const int b    = bid / (NCLS * 2);
    const int rem  = bid % (NCLS * 2);
    const int cls  = rem >> 1;
    const int half = rem & 1;
    const int t    = threadIdx.x;
    const int c    = t & 63;           // channel within half
    const int gq   = t >> 6;           // g-quarter 0..3

    if (t < 128) credv[t] = cpart[(size_t)(b * BPB + t) * NCLS + cls];

    const _Float16* pb = part + (size_t)(b * BPB + gq * 32) * KCH + cls * NCH + half * 64 + c;
    float s = 0.f;
#pragma unroll 8
    for (int g = 0; g < 32; ++g) s += (float)pb[(size_t)g * KCH];
    red[t] = s;
    __syncthreads();

    if (t < 64) {
        float cnt = credv[t] + credv[t + 64];
#pragma unroll
        for (int o = 32; o >= 1; o >>= 1) cnt += __shfl_xor(cnt, o, 64);
        const float sf = red[t] + red[t + 64] + red[t + 128] + red[t + 192];
        out[(size_t)b * KCH + (half * 64 + t) * NCLS + cls] = sf / (cnt + 1e-8f);  // (B,C,NCLS)
        if (t == 0 && half == 0) out[NF + b * NCLS + cls] = (cnt > 0.f) ? 1.f : 0.f;
    }
}

extern "C" void kernel_launch(void* const* d_in, const int* in_sizes, int n_in,
                              void* d_out, int out_size, void* d_ws, size_t ws_size,
                              hipStream_t stream) {
    const float* data  = (const float*)d_in[0];
    const int*   label = (const int*)d_in[1];
    float*     out   = (float*)d_out;
    _Float16*  part  = (_Float16*)d_ws;                          // NBLK*3072 f16 (6.3 MB)
    float*     cpart = (float*)(part + (size_t)NBLK * KCH);      // NBLK*24 f32

    fm_main<<<dim3(NBLK), dim3(256), 0, stream>>>(data, label, part, cpart);
    fm_final<<<dim3(NB * NCLS * 2), dim3(256), 0, stream>>>(part, cpart, out);
}